// Round 1
// baseline (140.684 us; speedup 1.0000x reference)
//
#include <hip/hip_runtime.h>

#define M_VOX 100000
#define N_VOXELS 200000
#define K_VOL 27
#define C_IN 32
#define C_OUT 64

typedef __bf16 bf16x8 __attribute__((ext_vector_type(8)));
typedef float floatx4 __attribute__((ext_vector_type(4)));

// One wave handles 16 output voxels x 64 output channels.
// Block = 256 threads = 4 waves = 64 voxels per block.
// For each of the 27 kernel offsets:
//   A-frag (per lane): gathered feats row m=(lane&15), channels quad*8..quad*8+7
//       (mfma_f32_16x16x32_bf16 A layout: A[m=lane&15][k=(lane>>4)*8+j])
//   B-frag: kernel[k][i][o] staged in LDS in fragment order, read as b128
//       (B layout: B[k=(lane>>4)*8+j][n=lane&15])
//   acc[t] += A * B_tile(t), t=0..3 covering 64 output channels.
// C/D layout: col=lane&15 (channel within tile), row=(lane>>4)*4+reg (voxel).
__global__ __launch_bounds__(256) void sparse_conv_mfma(
    const float* __restrict__ feats,
    const float* __restrict__ kernelw,
    const int* __restrict__ in_idx,
    const int* __restrict__ mask,
    float* __restrict__ out)
{
    // ldsB[buf][tile*64 + lane] = 8 bf16 that lane needs for that tile's B-frag
    __shared__ bf16x8 ldsB[2][256];

    const int tid  = threadIdx.x;
    const int lane = tid & 63;
    const int wv   = tid >> 6;
    const int col  = lane & 15;
    const int quad = lane >> 4;

    const int m0 = blockIdx.x * 64 + wv * 16;
    const bool active = (m0 < M_VOX);

    floatx4 acc0 = {0.f, 0.f, 0.f, 0.f};
    floatx4 acc1 = {0.f, 0.f, 0.f, 0.f};
    floatx4 acc2 = {0.f, 0.f, 0.f, 0.f};
    floatx4 acc3 = {0.f, 0.f, 0.f, 0.f};

    // Staging thread mapping: thread tid fills the fragment slot for
    // (tile = tid>>6, lane' = tid&63), i.e. elements
    // kernel[k][ (lane'>>4)*8 + j ][ (tid>>6)*16 + (lane'&15) ], j=0..7.
    // Global reads are 4x 64B segments per j-step (16 consecutive floats per
    // quad group); LDS write is one contiguous ds_write_b128 per thread.
    const int s_tile = tid >> 6;
    const int s_col  = tid & 15;
    const int s_quad = (tid >> 4) & 3;
    const float* kbase = kernelw + s_quad * 8 * C_OUT + s_tile * 16 + s_col;

    // stage offset 0 into buffer 0
    {
        const float* kp = kbase;  // k = 0
        bf16x8 b;
#pragma unroll
        for (int j = 0; j < 8; ++j) b[j] = (__bf16)kp[j * C_OUT];
        ldsB[0][tid] = b;
    }
    __syncthreads();

    for (int k = 0; k < K_VOL; ++k) {
        const int p = k & 1;

        if (active) {
            // gather A fragment
            const int mi = in_idx[k * M_VOX + m0 + col];
            const int mk = mask[k * M_VOX + m0 + col];
            bf16x8 afrag;
#pragma unroll
            for (int j = 0; j < 8; ++j) afrag[j] = (__bf16)0.0f;
            if (mk) {
                const float* src = feats + (long)mi * C_IN + quad * 8;
                floatx4 f0 = *(const floatx4*)(src);
                floatx4 f1 = *(const floatx4*)(src + 4);
#pragma unroll
                for (int j = 0; j < 4; ++j) {
                    afrag[j]     = (__bf16)f0[j];
                    afrag[4 + j] = (__bf16)f1[j];
                }
            }

            bf16x8 b0 = ldsB[p][0 * 64 + lane];
            bf16x8 b1 = ldsB[p][1 * 64 + lane];
            bf16x8 b2 = ldsB[p][2 * 64 + lane];
            bf16x8 b3 = ldsB[p][3 * 64 + lane];

            acc0 = __builtin_amdgcn_mfma_f32_16x16x32_bf16(afrag, b0, acc0, 0, 0, 0);
            acc1 = __builtin_amdgcn_mfma_f32_16x16x32_bf16(afrag, b1, acc1, 0, 0, 0);
            acc2 = __builtin_amdgcn_mfma_f32_16x16x32_bf16(afrag, b2, acc2, 0, 0, 0);
            acc3 = __builtin_amdgcn_mfma_f32_16x16x32_bf16(afrag, b3, acc3, 0, 0, 0);
        }

        // stage next offset into the other buffer
        if (k + 1 < K_VOL) {
            const float* kp = kbase + (k + 1) * C_IN * C_OUT;
            bf16x8 b;
#pragma unroll
            for (int j = 0; j < 8; ++j) b[j] = (__bf16)kp[j * C_OUT];
            ldsB[(k + 1) & 1][tid] = b;
        }
        __syncthreads();
    }

    if (active) {
        float* op = out + (long)(m0 + quad * 4) * C_OUT + col;
#pragma unroll
        for (int r = 0; r < 4; ++r) {
            op[r * C_OUT + 0]  = acc0[r];
            op[r * C_OUT + 16] = acc1[r];
            op[r * C_OUT + 32] = acc2[r];
            op[r * C_OUT + 48] = acc3[r];
        }
    }
}

extern "C" void kernel_launch(void* const* d_in, const int* in_sizes, int n_in,
                              void* d_out, int out_size, void* d_ws, size_t ws_size,
                              hipStream_t stream) {
    const float* feats   = (const float*)d_in[0];
    const float* kernelw = (const float*)d_in[1];
    const int*   in_idx  = (const int*)d_in[2];
    const int*   maskp   = (const int*)d_in[3];
    float*       out     = (float*)d_out;

    const int blocks = (M_VOX + 63) / 64;  // 64 voxels per block
    sparse_conv_mfma<<<dim3(blocks), dim3(256), 0, stream>>>(
        feats, kernelw, in_idx, maskp, out);
}

// Round 2
// 138.117 us; speedup vs baseline: 1.0186x; 1.0186x over previous
//
#include <hip/hip_runtime.h>

#define M_VOX   100000
#define N_VOX   200000
#define K_VOL   27
#define C_IN    32
#define C_OUT   64

typedef __bf16 bf16x8 __attribute__((ext_vector_type(8)));
typedef float  floatx4 __attribute__((ext_vector_type(4)));

// ---- d_ws layout ----
// featsB : (N_VOX+1) rows x 32 bf16 (64 B/row), row N_VOX is all zeros
//          bytes = 200001*64 = 12,800,064 (64B aligned)
// Bfrag  : 27 * 256 * bf16x8 (16 B)  = 110,592 B, fragment-layout bf16 weights
// midx   : 27 * M_VOX ints = 10,800,000 B  (mask fused: masked-out -> N_VOX)
#define FEATSB_BYTES  ((N_VOX + 1) * C_IN * 2)
#define BFRAG_OFF     FEATSB_BYTES
#define BFRAG_BYTES   (K_VOL * 256 * 16)
#define MIDX_OFF      (BFRAG_OFF + BFRAG_BYTES)

// ---------- prep 1: feats fp32 -> bf16, plus one zero row ----------
// one thread per 8 floats; (N_VOX+1)*4 chunks total
__global__ __launch_bounds__(256) void prep_feats(
    const float* __restrict__ feats, __bf16* __restrict__ featsB)
{
    const int c = blockIdx.x * 256 + threadIdx.x;
    const int nchunk = (N_VOX + 1) * 4;
    if (c >= nchunk) return;
    bf16x8 v;
    if (c < N_VOX * 4) {
        floatx4 f0 = *(const floatx4*)(feats + c * 8);
        floatx4 f1 = *(const floatx4*)(feats + c * 8 + 4);
#pragma unroll
        for (int j = 0; j < 4; ++j) { v[j] = (__bf16)f0[j]; v[4 + j] = (__bf16)f1[j]; }
    } else {
#pragma unroll
        for (int j = 0; j < 8; ++j) v[j] = (__bf16)0.0f;
    }
    *(bf16x8*)(featsB + c * 8) = v;
}

// ---------- prep 2: kernel weights fp32 -> bf16 fragment layout ----------
// block k (27 blocks), thread tid fills frag slot (tile=tid>>6, lane=tid&63):
//   element j = kernel[k][(lane>>4)&3 *8 + j][tile*16 + (lane&15)]
__global__ __launch_bounds__(256) void prep_weights(
    const float* __restrict__ kernelw, bf16x8* __restrict__ Bfrag)
{
    const int k    = blockIdx.x;
    const int tid  = threadIdx.x;
    const int tile = tid >> 6;
    const int col  = tid & 15;
    const int quad = (tid >> 4) & 3;
    const float* kp = kernelw + k * C_IN * C_OUT + quad * 8 * C_OUT + tile * 16 + col;
    bf16x8 b;
#pragma unroll
    for (int j = 0; j < 8; ++j) b[j] = (__bf16)kp[j * C_OUT];
    Bfrag[k * 256 + tid] = b;
}

// ---------- prep 3: fuse mask into idx ----------
__global__ __launch_bounds__(256) void prep_midx(
    const int* __restrict__ in_idx, const int* __restrict__ mask,
    int* __restrict__ midx)
{
    const int t = blockIdx.x * 256 + threadIdx.x;  // int4 granules, exact fit
    const int4 i4 = ((const int4*)in_idx)[t];
    const int4 m4 = ((const int4*)mask)[t];
    int4 o;
    o.x = m4.x ? i4.x : N_VOX;
    o.y = m4.y ? i4.y : N_VOX;
    o.z = m4.z ? i4.z : N_VOX;
    o.w = m4.w ? i4.w : N_VOX;
    ((int4*)midx)[t] = o;
}

// ---------- main: barrier-free gather + MFMA ----------
// One wave = 16 output voxels x 64 output channels. Block = 4 waves.
// All 27 midx loaded up front; A-gather and B-frag loads pipelined 1 deep.
__global__ __launch_bounds__(256) void sparse_conv_mfma(
    const __bf16* __restrict__ featsB,
    const bf16x8* __restrict__ Bfrag,
    const int* __restrict__ midx,
    float* __restrict__ out)
{
    const int tid  = threadIdx.x;
    const int lane = tid & 63;
    const int wv   = tid >> 6;
    const int col  = lane & 15;
    const int quad = lane >> 4;

    const int m0 = blockIdx.x * 64 + wv * 16;
    if (m0 >= M_VOX) return;   // M_VOX % 16 == 0: waves are all-or-nothing

    // hoist the entire index chain: 27 independent loads, all in flight
    int mi[K_VOL];
#pragma unroll
    for (int k = 0; k < K_VOL; ++k) mi[k] = midx[k * M_VOX + m0 + col];

    floatx4 acc0 = {0.f,0.f,0.f,0.f}, acc1 = {0.f,0.f,0.f,0.f};
    floatx4 acc2 = {0.f,0.f,0.f,0.f}, acc3 = {0.f,0.f,0.f,0.f};

    const bf16x8* bbase = Bfrag + lane;

    // software pipeline, depth 1
    bf16x8 a_n  = *(const bf16x8*)(featsB + (long)mi[0] * C_IN + quad * 8);
    bf16x8 b0_n = bbase[0*64], b1_n = bbase[1*64], b2_n = bbase[2*64], b3_n = bbase[3*64];

#pragma unroll
    for (int k = 0; k < K_VOL; ++k) {
        bf16x8 a = a_n, b0 = b0_n, b1 = b1_n, b2 = b2_n, b3 = b3_n;
        if (k + 1 < K_VOL) {
            a_n = *(const bf16x8*)(featsB + (long)mi[k + 1] * C_IN + quad * 8);
            const bf16x8* bb = bbase + (k + 1) * 256;
            b0_n = bb[0*64]; b1_n = bb[1*64]; b2_n = bb[2*64]; b3_n = bb[3*64];
        }
        acc0 = __builtin_amdgcn_mfma_f32_16x16x32_bf16(a, b0, acc0, 0, 0, 0);
        acc1 = __builtin_amdgcn_mfma_f32_16x16x32_bf16(a, b1, acc1, 0, 0, 0);
        acc2 = __builtin_amdgcn_mfma_f32_16x16x32_bf16(a, b2, acc2, 0, 0, 0);
        acc3 = __builtin_amdgcn_mfma_f32_16x16x32_bf16(a, b3, acc3, 0, 0, 0);
    }

    float* op = out + (long)(m0 + quad * 4) * C_OUT + col;
#pragma unroll
    for (int r = 0; r < 4; ++r) {
        op[r * C_OUT + 0]  = acc0[r];
        op[r * C_OUT + 16] = acc1[r];
        op[r * C_OUT + 32] = acc2[r];
        op[r * C_OUT + 48] = acc3[r];
    }
}

extern "C" void kernel_launch(void* const* d_in, const int* in_sizes, int n_in,
                              void* d_out, int out_size, void* d_ws, size_t ws_size,
                              hipStream_t stream) {
    const float* feats   = (const float*)d_in[0];
    const float* kernelw = (const float*)d_in[1];
    const int*   in_idx  = (const int*)d_in[2];
    const int*   maskp   = (const int*)d_in[3];
    float*       out     = (float*)d_out;

    __bf16* featsB = (__bf16*)d_ws;
    bf16x8* BfragP = (bf16x8*)((char*)d_ws + BFRAG_OFF);
    int*    midxP  = (int*)((char*)d_ws + MIDX_OFF);

    {   // feats fp32->bf16 (+zero row): (N_VOX+1)*4 chunks of 8 floats
        const int nchunk = (N_VOX + 1) * 4;
        prep_feats<<<dim3((nchunk + 255) / 256), dim3(256), 0, stream>>>(feats, featsB);
    }
    prep_weights<<<dim3(K_VOL), dim3(256), 0, stream>>>(kernelw, BfragP);
    {   // 27*M_VOX ints / 4 per thread = 675000 threads exactly
        const int nthr = K_VOL * M_VOX / 4;
        prep_midx<<<dim3(nthr / 256 + 1), dim3(256), 0, stream>>>(in_idx, maskp, midxP);
    }

    const int blocks = (M_VOX + 63) / 64;
    sparse_conv_mfma<<<dim3(blocks), dim3(256), 0, stream>>>(featsB, BfragP, midxP, out);
}

// Round 3
// 137.209 us; speedup vs baseline: 1.0253x; 1.0066x over previous
//
#include <hip/hip_runtime.h>

#define M_VOX   100000
#define N_VOX   200000
#define K_VOL   27
#define C_IN    32
#define C_OUT   64
#define DEPTH   14          // gather pipeline depth (outstanding loads per wave)

typedef __bf16 bf16x8 __attribute__((ext_vector_type(8)));
typedef float  floatx4 __attribute__((ext_vector_type(4)));

// ---- d_ws layout ----
// featsB : (N_VOX+1) rows x 32 bf16 (64 B/row), row N_VOX all-zero
// Bfrag  : 27 * 256 * 16 B  bf16 weights in MFMA fragment order
#define FEATSB_BYTES  ((N_VOX + 1) * C_IN * 2)          // 12,800,064 (64B mult)
#define BFRAG_OFF     FEATSB_BYTES

// ---------- fused prep: feats fp32->bf16 (+zero row)  |  weights->frag ----------
#define FEAT_CHUNKS   ((N_VOX + 1) * 4)                 // 8-float chunks
#define FEAT_BLOCKS   ((FEAT_CHUNKS + 255) / 256)       // 3126
__global__ __launch_bounds__(256) void prep_all(
    const float* __restrict__ feats, const float* __restrict__ kernelw,
    __bf16* __restrict__ featsB, bf16x8* __restrict__ Bfrag)
{
    if (blockIdx.x < FEAT_BLOCKS) {
        const int c = blockIdx.x * 256 + threadIdx.x;
        if (c >= FEAT_CHUNKS) return;
        bf16x8 v;
        if (c < N_VOX * 4) {
            floatx4 f0 = *(const floatx4*)(feats + c * 8);
            floatx4 f1 = *(const floatx4*)(feats + c * 8 + 4);
#pragma unroll
            for (int j = 0; j < 4; ++j) { v[j] = (__bf16)f0[j]; v[4 + j] = (__bf16)f1[j]; }
        } else {
#pragma unroll
            for (int j = 0; j < 8; ++j) v[j] = (__bf16)0.0f;
        }
        *(bf16x8*)(featsB + c * 8) = v;
    } else {
        // weight fragment: block k, thread tid -> slot (tile=tid>>6, lane=tid&63)
        // element j = kernel[k][((lane>>4)&3)*8 + j][tile*16 + (lane&15)]
        const int k    = blockIdx.x - FEAT_BLOCKS;
        const int tid  = threadIdx.x;
        const int tile = tid >> 6;
        const int col  = tid & 15;
        const int quad = (tid >> 4) & 3;
        const float* kp = kernelw + k * C_IN * C_OUT + quad * 8 * C_OUT + tile * 16 + col;
        bf16x8 b;
#pragma unroll
        for (int j = 0; j < 8; ++j) b[j] = (__bf16)kp[j * C_OUT];
        Bfrag[k * 256 + tid] = b;
    }
}

// ---------- main: deep-pipelined gather + MFMA, barrier-free ----------
// One wave = 16 output voxels x 64 output channels; block = 4 waves.
// A-frag layout (16x16x32 bf16): A[m=lane&15][k=(lane>>4)*8+j]
// B-frag read straight from Bfrag in fragment order (uniform addr, L1/L2-hot)
// C/D: col=lane&15, row=(lane>>4)*4+reg
__global__ __launch_bounds__(256, 3) void sparse_conv_mfma(
    const __bf16* __restrict__ featsB,
    const bf16x8* __restrict__ Bfrag,
    const int* __restrict__ in_idx,
    const int* __restrict__ mask,
    float* __restrict__ out)
{
    const int tid  = threadIdx.x;
    const int lane = tid & 63;
    const int wv   = tid >> 6;
    const int col  = lane & 15;
    const int quad = lane >> 4;

    const int m0 = blockIdx.x * 64 + wv * 16;
    if (m0 >= M_VOX) return;   // M_VOX % 16 == 0: waves all-or-nothing

    // Load the whole index/mask chain up front (54 independent coalesced loads),
    // fuse mask by redirecting to the all-zero row N_VOX.
    int mi[K_VOL];
#pragma unroll
    for (int k = 0; k < K_VOL; ++k) {
        const int ix = in_idx[k * M_VOX + m0 + col];
        const int mk = mask[k * M_VOX + m0 + col];
        mi[k] = mk ? ix : N_VOX;
    }

    const __bf16* fbase = featsB + quad * 8;   // + mi*32 elements per gather

    // Prime the gather pipeline: DEPTH outstanding scattered 16B loads.
    bf16x8 A[DEPTH];
#pragma unroll
    for (int k = 0; k < DEPTH; ++k)
        A[k] = *(const bf16x8*)(fbase + (size_t)mi[k] * C_IN);

    floatx4 acc0 = {0.f,0.f,0.f,0.f}, acc1 = {0.f,0.f,0.f,0.f};
    floatx4 acc2 = {0.f,0.f,0.f,0.f}, acc3 = {0.f,0.f,0.f,0.f};

    const bf16x8* bbase = Bfrag + lane;
    // B prefetch, depth 1 (uniform per-wave addresses; L2-resident 110 KB table)
    bf16x8 nb0 = bbase[0*64], nb1 = bbase[1*64], nb2 = bbase[2*64], nb3 = bbase[3*64];

#pragma unroll
    for (int k = 0; k < K_VOL; ++k) {
        const int s = k % DEPTH;
        bf16x8 a  = A[s];
        bf16x8 b0 = nb0, b1 = nb1, b2 = nb2, b3 = nb3;

        if (k + DEPTH < K_VOL)
            A[s] = *(const bf16x8*)(fbase + (size_t)mi[k + DEPTH] * C_IN);
        if (k + 1 < K_VOL) {
            const bf16x8* bb = bbase + (k + 1) * 256;
            nb0 = bb[0*64]; nb1 = bb[1*64]; nb2 = bb[2*64]; nb3 = bb[3*64];
        }

        acc0 = __builtin_amdgcn_mfma_f32_16x16x32_bf16(a, b0, acc0, 0, 0, 0);
        acc1 = __builtin_amdgcn_mfma_f32_16x16x32_bf16(a, b1, acc1, 0, 0, 0);
        acc2 = __builtin_amdgcn_mfma_f32_16x16x32_bf16(a, b2, acc2, 0, 0, 0);
        acc3 = __builtin_amdgcn_mfma_f32_16x16x32_bf16(a, b3, acc3, 0, 0, 0);
    }

    float* op = out + (size_t)(m0 + quad * 4) * C_OUT + col;
#pragma unroll
    for (int r = 0; r < 4; ++r) {
        op[r * C_OUT + 0]  = acc0[r];
        op[r * C_OUT + 16] = acc1[r];
        op[r * C_OUT + 32] = acc2[r];
        op[r * C_OUT + 48] = acc3[r];
    }
}

extern "C" void kernel_launch(void* const* d_in, const int* in_sizes, int n_in,
                              void* d_out, int out_size, void* d_ws, size_t ws_size,
                              hipStream_t stream) {
    const float* feats   = (const float*)d_in[0];
    const float* kernelw = (const float*)d_in[1];
    const int*   in_idx  = (const int*)d_in[2];
    const int*   maskp   = (const int*)d_in[3];
    float*       out     = (float*)d_out;

    __bf16* featsB = (__bf16*)d_ws;
    bf16x8* BfragP = (bf16x8*)((char*)d_ws + BFRAG_OFF);

    prep_all<<<dim3(FEAT_BLOCKS + K_VOL), dim3(256), 0, stream>>>(
        feats, kernelw, featsB, BfragP);

    const int blocks = (M_VOX + 63) / 64;
    sparse_conv_mfma<<<dim3(blocks), dim3(256), 0, stream>>>(
        featsB, BfragP, in_idx, maskp, out);
}

// Round 4
// 122.074 us; speedup vs baseline: 1.1525x; 1.1240x over previous
//
#include <hip/hip_runtime.h>

#define M_VOX   100000
#define N_VOX   200000
#define K_VOL   27
#define C_IN    32
#define C_OUT   64

#define STG0        14                 // offsets staged in LDS pass 0
#define BLK_THREADS 1024               // 16 waves; block covers 256 voxels
#define VOX_PER_BLK 256

typedef __bf16 bf16x8 __attribute__((ext_vector_type(8)));
typedef float  floatx4 __attribute__((ext_vector_type(4)));

// ---- d_ws layout ----
// featsB : (N_VOX+1) rows x 32 bf16 (64 B/row), row N_VOX all-zero
// Bfrag  : 27 * 256 * 16 B bf16 weights in MFMA fragment order
#define FEATSB_BYTES  ((N_VOX + 1) * C_IN * 2)
#define BFRAG_OFF     FEATSB_BYTES

// ---------- fused prep: feats fp32->bf16 (+zero row) | weights->frag ----------
#define FEAT_CHUNKS   ((N_VOX + 1) * 4)
#define FEAT_BLOCKS   ((FEAT_CHUNKS + 255) / 256)
__global__ __launch_bounds__(256) void prep_all(
    const float* __restrict__ feats, const float* __restrict__ kernelw,
    __bf16* __restrict__ featsB, bf16x8* __restrict__ Bfrag)
{
    if (blockIdx.x < FEAT_BLOCKS) {
        const int c = blockIdx.x * 256 + threadIdx.x;
        if (c >= FEAT_CHUNKS) return;
        bf16x8 v;
        if (c < N_VOX * 4) {
            floatx4 f0 = *(const floatx4*)(feats + c * 8);
            floatx4 f1 = *(const floatx4*)(feats + c * 8 + 4);
#pragma unroll
            for (int j = 0; j < 4; ++j) { v[j] = (__bf16)f0[j]; v[4 + j] = (__bf16)f1[j]; }
        } else {
#pragma unroll
            for (int j = 0; j < 8; ++j) v[j] = (__bf16)0.0f;
        }
        *(bf16x8*)(featsB + c * 8) = v;
    } else {
        // weight frag: block k, thread tid -> slot (tile=tid>>6, lane=tid&63)
        // element j = kernel[k][((lane>>4)&3)*8 + j][tile*16 + (lane&15)]
        const int k    = blockIdx.x - FEAT_BLOCKS;
        const int tid  = threadIdx.x;
        const int tile = tid >> 6;
        const int col  = tid & 15;
        const int quad = (tid >> 4) & 3;
        const float* kp = kernelw + k * C_IN * C_OUT + quad * 8 * C_OUT + tile * 16 + col;
        bf16x8 b;
#pragma unroll
        for (int j = 0; j < 8; ++j) b[j] = (__bf16)kp[j * C_OUT];
        Bfrag[k * 256 + tid] = b;
    }
}

// ---------- main ----------
// Block = 1024 threads = 16 waves; wave = 16 voxels x 64 out-channels.
// B-frags live in LDS (two stages of <=14 offsets, 57,344 B), so the weight
// table is read from global once per BLOCK (43 MB total) instead of once per
// wave-offset (675 MB) — that redundant L1/L2 stream was the r2/r3 limiter.
// A-frag gather: lane (col,quad) reads featsB[mi[k]] + quad*16B (bf16x8).
// C/D layout: col=lane&15 (channel in tile), row=quad*4+reg (voxel).
__global__ __launch_bounds__(BLK_THREADS) void sparse_conv_mfma(
    const __bf16* __restrict__ featsB,
    const bf16x8* __restrict__ BfragG,
    const int* __restrict__ in_idx,
    const int* __restrict__ mask,
    float* __restrict__ out)
{
    __shared__ bf16x8 ldsB[STG0 * 256];   // 57,344 B

    const int tid  = threadIdx.x;
    const int lane = tid & 63;
    const int wv   = tid >> 6;
    const int col  = lane & 15;
    const int quad = lane >> 4;

    const int m0 = blockIdx.x * VOX_PER_BLK + wv * 16;
    const bool active = (m0 < M_VOX);   // M_VOX%16==0: waves all-or-nothing

    // stage offsets 0..STG0-1 (all waves participate — barrier safety)
#pragma unroll 2
    for (int i = tid; i < STG0 * 256; i += BLK_THREADS) ldsB[i] = BfragG[i];

    // index chain up front: 54 coalesced loads, mask fused -> zero row N_VOX
    int mi[K_VOL];
    if (active) {
#pragma unroll
        for (int k = 0; k < K_VOL; ++k) {
            const int ix = in_idx[k * M_VOX + m0 + col];
            const int mk = mask[k * M_VOX + m0 + col];
            mi[k] = mk ? ix : N_VOX;
        }
    }
    __syncthreads();

    floatx4 acc0 = {0.f,0.f,0.f,0.f}, acc1 = {0.f,0.f,0.f,0.f};
    floatx4 acc2 = {0.f,0.f,0.f,0.f}, acc3 = {0.f,0.f,0.f,0.f};

    const __bf16*  fbase = featsB + quad * 8;
    const bf16x8*  lbase = ldsB + lane;

    bf16x8 a_n;
    if (active) a_n = *(const bf16x8*)(fbase + (size_t)mi[0] * C_IN);

    // ---- stage 0: offsets 0..13 ----
    if (active) {
#pragma unroll
        for (int k = 0; k < STG0; ++k) {
            bf16x8 a  = a_n;
            bf16x8 b0 = lbase[k * 256 + 0 * 64];
            bf16x8 b1 = lbase[k * 256 + 1 * 64];
            bf16x8 b2 = lbase[k * 256 + 2 * 64];
            bf16x8 b3 = lbase[k * 256 + 3 * 64];
            if (k + 1 < K_VOL)
                a_n = *(const bf16x8*)(fbase + (size_t)mi[k + 1] * C_IN);
            acc0 = __builtin_amdgcn_mfma_f32_16x16x32_bf16(a, b0, acc0, 0, 0, 0);
            acc1 = __builtin_amdgcn_mfma_f32_16x16x32_bf16(a, b1, acc1, 0, 0, 0);
            acc2 = __builtin_amdgcn_mfma_f32_16x16x32_bf16(a, b2, acc2, 0, 0, 0);
            acc3 = __builtin_amdgcn_mfma_f32_16x16x32_bf16(a, b3, acc3, 0, 0, 0);
        }
    }

    // ---- restage: offsets 14..26 ----
    __syncthreads();
#pragma unroll 2
    for (int i = tid; i < (K_VOL - STG0) * 256; i += BLK_THREADS)
        ldsB[i] = BfragG[STG0 * 256 + i];
    __syncthreads();

    // ---- stage 1: offsets 14..26 ----
    if (active) {
#pragma unroll
        for (int k = STG0; k < K_VOL; ++k) {
            bf16x8 a  = a_n;
            bf16x8 b0 = lbase[(k - STG0) * 256 + 0 * 64];
            bf16x8 b1 = lbase[(k - STG0) * 256 + 1 * 64];
            bf16x8 b2 = lbase[(k - STG0) * 256 + 2 * 64];
            bf16x8 b3 = lbase[(k - STG0) * 256 + 3 * 64];
            if (k + 1 < K_VOL)
                a_n = *(const bf16x8*)(fbase + (size_t)mi[k + 1] * C_IN);
            acc0 = __builtin_amdgcn_mfma_f32_16x16x32_bf16(a, b0, acc0, 0, 0, 0);
            acc1 = __builtin_amdgcn_mfma_f32_16x16x32_bf16(a, b1, acc1, 0, 0, 0);
            acc2 = __builtin_amdgcn_mfma_f32_16x16x32_bf16(a, b2, acc2, 0, 0, 0);
            acc3 = __builtin_amdgcn_mfma_f32_16x16x32_bf16(a, b3, acc3, 0, 0, 0);
        }

        float* op = out + (size_t)(m0 + quad * 4) * C_OUT + col;
#pragma unroll
        for (int r = 0; r < 4; ++r) {
            op[r * C_OUT + 0]  = acc0[r];
            op[r * C_OUT + 16] = acc1[r];
            op[r * C_OUT + 32] = acc2[r];
            op[r * C_OUT + 48] = acc3[r];
        }
    }
}

extern "C" void kernel_launch(void* const* d_in, const int* in_sizes, int n_in,
                              void* d_out, int out_size, void* d_ws, size_t ws_size,
                              hipStream_t stream) {
    const float* feats   = (const float*)d_in[0];
    const float* kernelw = (const float*)d_in[1];
    const int*   in_idx  = (const int*)d_in[2];
    const int*   maskp   = (const int*)d_in[3];
    float*       out     = (float*)d_out;

    __bf16* featsB = (__bf16*)d_ws;
    bf16x8* BfragP = (bf16x8*)((char*)d_ws + BFRAG_OFF);

    prep_all<<<dim3(FEAT_BLOCKS + K_VOL), dim3(256), 0, stream>>>(
        feats, kernelw, featsB, BfragP);

    const int blocks = (M_VOX + VOX_PER_BLK - 1) / VOX_PER_BLK;   // 391
    sparse_conv_mfma<<<dim3(blocks), dim3(BLK_THREADS), 0, stream>>>(
        featsB, BfragP, in_idx, maskp, out);
}